// Round 6
// baseline (348.135 us; speedup 1.0000x reference)
//
#include <hip/hip_runtime.h>
#include <hip/hip_bf16.h>

// Chamfer loss: B=8, P=32, N=M=1024, fp32 in, scalar fp32 out.
// Reference quirk: x[bp,m,c] = rp[bp, (3m+c)%M, (3m+c)>>10]  (torch permute+reshape).
//
// R5: occupancy attack. 1024 blocks x 512 threads (4 row-blocks/bp, 256 rows
// each) -> 32 waves/CU (8/SIMD) vs 16 before. RB=8 rows per ds_read_b128
// halves LDS-pipe time. LDS ~21 KB/block (yS 16K + int-key colmin 4K) so
// 4 blocks/CU fit. Row-mins complete per block -> atomicAdd. Col-mins:
// LDS atomicMin (monotone int keys) -> global atomicMin in d_ws; last block
// per bp (device counter) decodes + sums -> atomicAdd. No second kernel.

#define MM 1024
#define NN 1024
#define THREADS 512
#define NWAVES 8              // per block
#define RBLK 4                // row-blocks per bp
#define ROWS_PER_BLOCK 256
#define ROWS_PER_WAVE 32
#define RB 8                  // rows per inner batch
#define CPL 16                // col-chunks per lane
#define FINF 3.4e38f
#define KEY_INIT 0x7F7F7F7F   // memset 0x7F; > any real key

__device__ __forceinline__ int fkey(float f) {          // monotone float->int
    int b = __float_as_int(f);
    return (b >= 0) ? b : (b ^ 0x7FFFFFFF);
}
__device__ __forceinline__ float funkey(int k) {        // involution
    return __int_as_float((k >= 0) ? k : (k ^ 0x7FFFFFFF));
}

template <int CTRL>
__device__ __forceinline__ float dpp_ror_min(float v) {
    int vi = __float_as_int(v);
    int t  = __builtin_amdgcn_update_dpp(vi, vi, CTRL, 0xf, 0xf, true);
    return fminf(v, __int_as_float(t));
}
__device__ __forceinline__ float wave_min64(float v, int xaddr32) {
    v = dpp_ror_min<0x121>(v);   // row_ror:1 (16-lane rows)
    v = dpp_ror_min<0x122>(v);
    v = dpp_ror_min<0x124>(v);
    v = dpp_ror_min<0x128>(v);
    int s = __builtin_amdgcn_ds_swizzle(__float_as_int(v), 0x401F); // xor16
    v = fminf(v, __int_as_float(s));
    int p = __builtin_amdgcn_ds_bpermute(xaddr32, __float_as_int(v));
    return fminf(v, __int_as_float(p));  // xor 32
}

__global__ __launch_bounds__(THREADS, 8)
void chamfer_kernel(const float* __restrict__ nrf,   // (BP,N,3) -> y
                    const float* __restrict__ rp,    // (BP,M,3) -> x (scrambled)
                    float* __restrict__ out,
                    int* __restrict__ wsKeys,        // (BP,NN) col-min keys
                    int* __restrict__ wsCnt,         // (BP) done counters
                    float inv_bpm, float inv_bpn) {
    const int bp   = blockIdx.x >> 2;
    const int rb   = blockIdx.x & 3;
    const int tid  = threadIdx.x;
    const int lane = tid & 63;
    const int wave = tid >> 6;
    const int xaddr32 = ((lane ^ 32) << 2);

    __shared__ float4 yS[NN];            // 16 KB (y, ||y||^2)
    __shared__ float4 xS[ROWS_PER_BLOCK];//  4 KB (-2x, ||x||^2)
    __shared__ int    colminI[NN];       //  4 KB int-key col mins
    __shared__ float  rowsumS[NWAVES];
    __shared__ int    lastS;

    const float* rpB = rp  + (size_t)bp * MM * 3;
    const float* yB  = nrf + (size_t)bp * NN * 3;
    int* keysB = wsKeys + (size_t)bp * NN;

    // Phase 0: yS (2 cols/thread), colminI init, xS (rows of this block).
    #pragma unroll
    for (int t = tid; t < NN; t += THREADS) {
        float a = yB[t * 3 + 0], b = yB[t * 3 + 1], c = yB[t * 3 + 2];
        yS[t] = make_float4(a, b, c, a * a + b * b + c * c);
        colminI[t] = KEY_INIT;
    }
    if (tid < ROWS_PER_BLOCK) {
        const int m = rb * ROWS_PER_BLOCK + tid;
        const int k = 3 * m;
        float a = rpB[((k + 0) & (MM - 1)) * 3 + ((k + 0) >> 10)];
        float b = rpB[((k + 1) & (MM - 1)) * 3 + ((k + 1) >> 10)];
        float c = rpB[((k + 2) & (MM - 1)) * 3 + ((k + 2) >> 10)];
        xS[tid] = make_float4(-2.0f * a, -2.0f * b, -2.0f * c,
                              a * a + b * b + c * c);
    }
    __syncthreads();

    float colmin[CPL];
    #pragma unroll
    for (int i = 0; i < CPL; ++i) colmin[i] = FINF;

    float rowsum = 0.0f;
    const int m0 = wave * ROWS_PER_WAVE;
    for (int r0 = 0; r0 < ROWS_PER_WAVE; r0 += RB) {
        float4 x[RB];
        #pragma unroll
        for (int j = 0; j < RB; ++j) x[j] = xS[m0 + r0 + j];  // broadcast

        float rmin[RB];
        #pragma unroll
        for (int j = 0; j < RB; ++j) rmin[j] = FINF;

        #pragma unroll
        for (int i = 0; i < CPL; ++i) {
            const float4 yv = yS[i * 64 + lane];   // conflict-free b128
            float e[RB];
            #pragma unroll
            for (int j = 0; j < RB; ++j) {
                e[j] = __builtin_fmaf(x[j].x, yv.x,
                        __builtin_fmaf(x[j].y, yv.y,
                         __builtin_fmaf(x[j].z, yv.z, yv.w)));
                rmin[j] = fminf(rmin[j], e[j]);
            }
            float m01 = fminf(e[0] + x[0].w, e[1] + x[1].w);
            float m23 = fminf(e[2] + x[2].w, e[3] + x[3].w);
            float m45 = fminf(e[4] + x[4].w, e[5] + x[5].w);
            float m67 = fminf(e[6] + x[6].w, e[7] + x[7].w);
            colmin[i] = fminf(fminf(colmin[i], fminf(m01, m23)),
                              fminf(m45, m67));
        }

        #pragma unroll
        for (int j = 0; j < RB; ++j) rmin[j] = wave_min64(rmin[j], xaddr32);
        #pragma unroll
        for (int j = 0; j < RB; ++j) rowsum += x[j].w + rmin[j];
    }

    // Per-wave col-min merge into LDS int keys.
    #pragma unroll
    for (int i = 0; i < CPL; ++i)
        atomicMin(&colminI[i * 64 + lane], fkey(colmin[i]));
    if (lane == 0) rowsumS[wave] = rowsum;
    __syncthreads();

    // Global col-min merge + block rowsum.
    #pragma unroll
    for (int t = tid; t < NN; t += THREADS)
        atomicMin(&keysB[t], colminI[t]);
    if (tid == 0) {
        float rs = 0.0f;
        #pragma unroll
        for (int w = 0; w < NWAVES; ++w) rs += rowsumS[w];
        atomicAdd(out, rs * inv_bpm);
        __threadfence();
        lastS = (atomicAdd(&wsCnt[bp], 1) == RBLK - 1);
    }
    __syncthreads();

    // Last block of this bp: decode + sum column mins.
    if (lastS) {
        __threadfence();
        float cs = 0.0f;
        #pragma unroll
        for (int t = tid; t < NN; t += THREADS) {
            int k = atomicMin(&keysB[t], 0x7FFFFFFF);  // device-scope read
            cs += funkey(k);
        }
        #pragma unroll
        for (int off = 32; off > 0; off >>= 1)
            cs += __shfl_xor(cs, off, 64);
        if (lane == 0) rowsumS[wave] = cs;   // reuse
        __syncthreads();
        if (tid == 0) {
            float s = 0.0f;
            #pragma unroll
            for (int w = 0; w < NWAVES; ++w) s += rowsumS[w];
            atomicAdd(out, s * inv_bpn);
        }
    }
}

extern "C" void kernel_launch(void* const* d_in, const int* in_sizes, int n_in,
                              void* d_out, int out_size, void* d_ws, size_t ws_size,
                              hipStream_t stream) {
    const float* nrf = (const float*)d_in[0];  // (B,P,N,3)
    const float* rp  = (const float*)d_in[1];  // (B,P,M,3)
    float* out = (float*)d_out;

    const int BP = in_sizes[1] / (MM * 3);     // 256
    const float inv_bpm = 1.0f / (float)(BP * MM);
    const float inv_bpn = 1.0f / (float)(BP * NN);

    int* wsKeys = (int*)d_ws;                  // BP*NN ints = 1 MB
    int* wsCnt  = wsKeys + (size_t)BP * NN;    // BP ints

    (void)hipMemsetAsync(out, 0, sizeof(float), stream);
    (void)hipMemsetAsync(wsKeys, 0x7F, (size_t)BP * NN * sizeof(int), stream);
    (void)hipMemsetAsync(wsCnt, 0, (size_t)BP * sizeof(int), stream);
    chamfer_kernel<<<BP * RBLK, THREADS, 0, stream>>>(
        nrf, rp, out, wsKeys, wsCnt, inv_bpm, inv_bpn);
}

// Round 7
// 339.469 us; speedup vs baseline: 1.0255x; 1.0255x over previous
//
#include <hip/hip_runtime.h>
#include <hip/hip_bf16.h>

// Chamfer loss: B=8, P=32, N=M=1024, fp32 in, scalar fp32 out.
// Reference quirk: x[bp,m,c] = rp[bp, (3m+c)%M, (3m+c)>>10]  (torch permute+reshape).
//
// R6: R5's occupancy attack, spill-safe. R5 died from launch_bounds(512,8)
// -> 64-VGPR cap vs ~76 live floats -> 264 MB scratch spill (VGPR_Count=32,
// VALUBusy 17%). Fix: RB=4 (x[4] = 16 regs, ~68 live total) +
// launch_bounds(512,6) -> ~85-VGPR cap, 24 waves/CU (3 blocks/CU, 72 KB LDS).
// Column loop unrolled x2 so rmin update fuses to v_min3.
// 1024 blocks x 512 threads: 4 row-blocks/bp, 256 rows each; y + colmin in
// LDS; col-mins merge via LDS atomicMin (monotone int keys) -> global
// atomicMin in d_ws; last block per bp decodes + sums.

#define MM 1024
#define NN 1024
#define THREADS 512
#define NWAVES 8              // per block
#define RBLK 4                // row-blocks per bp
#define ROWS_PER_BLOCK 256
#define ROWS_PER_WAVE 32
#define RB 4                  // rows per inner batch
#define CPL 16                // col-chunks per lane
#define FINF 3.4e38f
#define KEY_INIT 0x7F7F7F7F   // memset 0x7F; > any real key

__device__ __forceinline__ int fkey(float f) {          // monotone float->int
    int b = __float_as_int(f);
    return (b >= 0) ? b : (b ^ 0x7FFFFFFF);
}
__device__ __forceinline__ float funkey(int k) {        // involution
    return __int_as_float((k >= 0) ? k : (k ^ 0x7FFFFFFF));
}

template <int CTRL>
__device__ __forceinline__ float dpp_ror_min(float v) {
    int vi = __float_as_int(v);
    int t  = __builtin_amdgcn_update_dpp(vi, vi, CTRL, 0xf, 0xf, true);
    return fminf(v, __int_as_float(t));
}
__device__ __forceinline__ float wave_min64(float v, int xaddr32) {
    v = dpp_ror_min<0x121>(v);   // row_ror:1 (16-lane rows)
    v = dpp_ror_min<0x122>(v);
    v = dpp_ror_min<0x124>(v);
    v = dpp_ror_min<0x128>(v);
    int s = __builtin_amdgcn_ds_swizzle(__float_as_int(v), 0x401F); // xor16
    v = fminf(v, __int_as_float(s));
    int p = __builtin_amdgcn_ds_bpermute(xaddr32, __float_as_int(v));
    return fminf(v, __int_as_float(p));  // xor 32
}

__global__ __launch_bounds__(THREADS, 6)
void chamfer_kernel(const float* __restrict__ nrf,   // (BP,N,3) -> y
                    const float* __restrict__ rp,    // (BP,M,3) -> x (scrambled)
                    float* __restrict__ out,
                    int* __restrict__ wsKeys,        // (BP,NN) col-min keys
                    int* __restrict__ wsCnt,         // (BP) done counters
                    float inv_bpm, float inv_bpn) {
    const int bp   = blockIdx.x >> 2;
    const int rb   = blockIdx.x & 3;
    const int tid  = threadIdx.x;
    const int lane = tid & 63;
    const int wave = tid >> 6;
    const int xaddr32 = ((lane ^ 32) << 2);

    __shared__ float4 yS[NN];            // 16 KB (y, ||y||^2)
    __shared__ float4 xS[ROWS_PER_BLOCK];//  4 KB (-2x, ||x||^2)
    __shared__ int    colminI[NN];       //  4 KB int-key col mins
    __shared__ float  rowsumS[NWAVES];
    __shared__ int    lastS;

    const float* rpB = rp  + (size_t)bp * MM * 3;
    const float* yB  = nrf + (size_t)bp * NN * 3;
    int* keysB = wsKeys + (size_t)bp * NN;

    // Phase 0: yS (2 cols/thread), colminI init, xS (this block's rows).
    #pragma unroll
    for (int t = tid; t < NN; t += THREADS) {
        float a = yB[t * 3 + 0], b = yB[t * 3 + 1], c = yB[t * 3 + 2];
        yS[t] = make_float4(a, b, c, a * a + b * b + c * c);
        colminI[t] = KEY_INIT;
    }
    if (tid < ROWS_PER_BLOCK) {
        const int m = rb * ROWS_PER_BLOCK + tid;
        const int k = 3 * m;
        float a = rpB[((k + 0) & (MM - 1)) * 3 + ((k + 0) >> 10)];
        float b = rpB[((k + 1) & (MM - 1)) * 3 + ((k + 1) >> 10)];
        float c = rpB[((k + 2) & (MM - 1)) * 3 + ((k + 2) >> 10)];
        xS[tid] = make_float4(-2.0f * a, -2.0f * b, -2.0f * c,
                              a * a + b * b + c * c);
    }
    __syncthreads();

    float colmin[CPL];
    #pragma unroll
    for (int i = 0; i < CPL; ++i) colmin[i] = FINF;

    float rowsum = 0.0f;
    const int m0 = wave * ROWS_PER_WAVE;
    for (int r0 = 0; r0 < ROWS_PER_WAVE; r0 += RB) {
        float4 x[RB];
        #pragma unroll
        for (int j = 0; j < RB; ++j) x[j] = xS[m0 + r0 + j];  // broadcast

        float rmin[RB];
        #pragma unroll
        for (int j = 0; j < RB; ++j) rmin[j] = FINF;

        #pragma unroll
        for (int i = 0; i < CPL; i += 2) {
            const float4 yv0 = yS[(i + 0) * 64 + lane];  // conflict-free b128
            const float4 yv1 = yS[(i + 1) * 64 + lane];
            float e0[RB], e1[RB];
            #pragma unroll
            for (int j = 0; j < RB; ++j) {
                e0[j] = __builtin_fmaf(x[j].x, yv0.x,
                         __builtin_fmaf(x[j].y, yv0.y,
                          __builtin_fmaf(x[j].z, yv0.z, yv0.w)));
                e1[j] = __builtin_fmaf(x[j].x, yv1.x,
                         __builtin_fmaf(x[j].y, yv1.y,
                          __builtin_fmaf(x[j].z, yv1.z, yv1.w)));
                rmin[j] = fminf(fminf(rmin[j], e0[j]), e1[j]);  // v_min3
            }
            float a01 = fminf(e0[0] + x[0].w, e0[1] + x[1].w);
            float a23 = fminf(e0[2] + x[2].w, e0[3] + x[3].w);
            colmin[i + 0] = fminf(fminf(colmin[i + 0], a01), a23);  // v_min3
            float b01 = fminf(e1[0] + x[0].w, e1[1] + x[1].w);
            float b23 = fminf(e1[2] + x[2].w, e1[3] + x[3].w);
            colmin[i + 1] = fminf(fminf(colmin[i + 1], b01), b23);  // v_min3
        }

        #pragma unroll
        for (int j = 0; j < RB; ++j) rmin[j] = wave_min64(rmin[j], xaddr32);
        #pragma unroll
        for (int j = 0; j < RB; ++j) rowsum += x[j].w + rmin[j];
    }

    // Per-wave col-min merge into LDS int keys.
    #pragma unroll
    for (int i = 0; i < CPL; ++i)
        atomicMin(&colminI[i * 64 + lane], fkey(colmin[i]));
    if (lane == 0) rowsumS[wave] = rowsum;
    __syncthreads();

    // Global col-min merge + block rowsum.
    #pragma unroll
    for (int t = tid; t < NN; t += THREADS)
        atomicMin(&keysB[t], colminI[t]);
    if (tid == 0) {
        float rs = 0.0f;
        #pragma unroll
        for (int w = 0; w < NWAVES; ++w) rs += rowsumS[w];
        atomicAdd(out, rs * inv_bpm);
        __threadfence();
        lastS = (atomicAdd(&wsCnt[bp], 1) == RBLK - 1);
    }
    __syncthreads();

    // Last block of this bp: decode + sum column mins.
    if (lastS) {
        __threadfence();
        float cs = 0.0f;
        #pragma unroll
        for (int t = tid; t < NN; t += THREADS) {
            int k = atomicMin(&keysB[t], 0x7FFFFFFF);  // device-scope read
            cs += funkey(k);
        }
        #pragma unroll
        for (int off = 32; off > 0; off >>= 1)
            cs += __shfl_xor(cs, off, 64);
        if (lane == 0) rowsumS[wave] = cs;   // reuse
        __syncthreads();
        if (tid == 0) {
            float s = 0.0f;
            #pragma unroll
            for (int w = 0; w < NWAVES; ++w) s += rowsumS[w];
            atomicAdd(out, s * inv_bpn);
        }
    }
}

extern "C" void kernel_launch(void* const* d_in, const int* in_sizes, int n_in,
                              void* d_out, int out_size, void* d_ws, size_t ws_size,
                              hipStream_t stream) {
    const float* nrf = (const float*)d_in[0];  // (B,P,N,3)
    const float* rp  = (const float*)d_in[1];  // (B,P,M,3)
    float* out = (float*)d_out;

    const int BP = in_sizes[1] / (MM * 3);     // 256
    const float inv_bpm = 1.0f / (float)(BP * MM);
    const float inv_bpn = 1.0f / (float)(BP * NN);

    int* wsKeys = (int*)d_ws;                  // BP*NN ints = 1 MB
    int* wsCnt  = wsKeys + (size_t)BP * NN;    // BP ints

    (void)hipMemsetAsync(out, 0, sizeof(float), stream);
    (void)hipMemsetAsync(wsKeys, 0x7F, (size_t)BP * NN * sizeof(int), stream);
    (void)hipMemsetAsync(wsCnt, 0, (size_t)BP * sizeof(int), stream);
    chamfer_kernel<<<BP * RBLK, THREADS, 0, stream>>>(
        nrf, rp, out, wsKeys, wsCnt, inv_bpm, inv_bpn);
}

// Round 8
// 107.885 us; speedup vs baseline: 3.2269x; 3.1466x over previous
//
#include <hip/hip_runtime.h>
#include <hip/hip_bf16.h>

// Chamfer loss: B=8, P=32, N=M=1024, fp32 in, scalar fp32 out.
// Reference quirk: x[bp,m,c] = rp[bp, (3m+c)%M, (3m+c)>>10]  (torch permute+reshape).
//
// R7 = R4b (proven 49.9us, no spills) + RB=8 + unroll-2 min3 fusion.
// One block per bp (256 blocks x 1024 threads, 4 waves/SIMD, cap 128 VGPR —
// NO tighter launch_bounds: R5/R6 proved caps <128 spill ~200MB to scratch).
// Wave owns 64 rows; 8 rows per ds_read_b128 of y (LDS traffic 2 B/elem);
// rmin via v_min3(rmin,e0,e1); colmin via min3 trees. Row-min reduce:
// DPP row_ror chain + ds_swizzle xor16 + ds_bpermute xor32.

#define MM 1024
#define NN 1024
#define THREADS 1024
#define NWAVES 16
#define ROWS_PER_WAVE 64
#define RB 8
#define CPL 16                // col-chunks per lane (16*64 = 1024)
#define FINF 3.4e38f

template <int CTRL>
__device__ __forceinline__ float dpp_ror_min(float v) {
    int vi = __float_as_int(v);
    int t  = __builtin_amdgcn_update_dpp(vi, vi, CTRL, 0xf, 0xf, true);
    return fminf(v, __int_as_float(t));
}
__device__ __forceinline__ float wave_min64(float v, int xaddr32) {
    v = dpp_ror_min<0x121>(v);   // row_ror:1 (16-lane rows)
    v = dpp_ror_min<0x122>(v);
    v = dpp_ror_min<0x124>(v);
    v = dpp_ror_min<0x128>(v);
    int s = __builtin_amdgcn_ds_swizzle(__float_as_int(v), 0x401F); // xor16
    v = fminf(v, __int_as_float(s));
    int p = __builtin_amdgcn_ds_bpermute(xaddr32, __float_as_int(v));
    return fminf(v, __int_as_float(p));  // xor 32
}

__global__ __launch_bounds__(THREADS, 4)
void chamfer_kernel(const float* __restrict__ nrf,   // (BP, N, 3) -> y
                    const float* __restrict__ rp,    // (BP, M, 3) -> x (scrambled)
                    float* __restrict__ out,
                    float inv_bpm, float inv_bpn) {
    const int bp   = blockIdx.x;
    const int tid  = threadIdx.x;
    const int lane = tid & 63;
    const int wave = tid >> 6;
    const int xaddr32 = ((lane ^ 32) << 2);

    __shared__ float  rpS[MM * 3];            // 12 KB raw rp block
    __shared__ float4 xS[MM];                 // 16 KB per-row (-2x, ||x||^2)
    __shared__ float4 yS[NN];                 // 16 KB per-col (y, ||y||^2)
    __shared__ float  colminS[NWAVES][NN];    // 64 KB per-wave col-min partials
    __shared__ float  rowsumS[NWAVES];
    __shared__ float  csumS[NWAVES];

    const float* rpB = rp  + (size_t)bp * MM * 3;
    const float* yB  = nrf + (size_t)bp * NN * 3;

    // Phase 0: stage rp raw + build yS.
    for (int i = tid; i < MM * 3; i += THREADS) rpS[i] = rpB[i];
    {
        float a = yB[tid * 3 + 0];
        float b = yB[tid * 3 + 1];
        float c = yB[tid * 3 + 2];
        yS[tid] = make_float4(a, b, c, a * a + b * b + c * c);
    }
    __syncthreads();

    // Phase 1: per-row x params from scrambled view.
    {
        const int k = 3 * tid;
        float a = rpS[((k + 0) & (MM - 1)) * 3 + ((k + 0) >> 10)];
        float b = rpS[((k + 1) & (MM - 1)) * 3 + ((k + 1) >> 10)];
        float c = rpS[((k + 2) & (MM - 1)) * 3 + ((k + 2) >> 10)];
        xS[tid] = make_float4(-2.0f * a, -2.0f * b, -2.0f * c,
                              a * a + b * b + c * c);
    }
    __syncthreads();

    float colmin[CPL];
    #pragma unroll
    for (int i = 0; i < CPL; ++i) colmin[i] = FINF;

    float rowsum = 0.0f;
    const int m0 = wave * ROWS_PER_WAVE;
    for (int r0 = 0; r0 < ROWS_PER_WAVE; r0 += RB) {
        float4 x[RB];
        #pragma unroll
        for (int j = 0; j < RB; ++j) x[j] = xS[m0 + r0 + j];  // broadcast b128

        float rmin[RB];
        #pragma unroll
        for (int j = 0; j < RB; ++j) rmin[j] = FINF;

        #pragma unroll
        for (int i = 0; i < CPL; i += 2) {
            const float4 yv0 = yS[(i + 0) * 64 + lane];  // conflict-free b128
            const float4 yv1 = yS[(i + 1) * 64 + lane];
            float e0[RB], e1[RB];
            #pragma unroll
            for (int j = 0; j < RB; ++j) {
                e0[j] = __builtin_fmaf(x[j].x, yv0.x,
                         __builtin_fmaf(x[j].y, yv0.y,
                          __builtin_fmaf(x[j].z, yv0.z, yv0.w)));
                e1[j] = __builtin_fmaf(x[j].x, yv1.x,
                         __builtin_fmaf(x[j].y, yv1.y,
                          __builtin_fmaf(x[j].z, yv1.z, yv1.w)));
                rmin[j] = fminf(fminf(rmin[j], e0[j]), e1[j]);  // v_min3
            }
            // colmin trees (min3-friendly): 8 adds + ~4 mins per column.
            {
                float t0 = fminf(fminf(e0[0] + x[0].w, e0[1] + x[1].w),
                                 e0[2] + x[2].w);
                float t1 = fminf(fminf(e0[3] + x[3].w, e0[4] + x[4].w),
                                 e0[5] + x[5].w);
                float t2 = fminf(e0[6] + x[6].w, e0[7] + x[7].w);
                colmin[i + 0] = fminf(fminf(colmin[i + 0], t0), fminf(t1, t2));
            }
            {
                float t0 = fminf(fminf(e1[0] + x[0].w, e1[1] + x[1].w),
                                 e1[2] + x[2].w);
                float t1 = fminf(fminf(e1[3] + x[3].w, e1[4] + x[4].w),
                                 e1[5] + x[5].w);
                float t2 = fminf(e1[6] + x[6].w, e1[7] + x[7].w);
                colmin[i + 1] = fminf(fminf(colmin[i + 1], t0), fminf(t1, t2));
            }
        }

        // 8 interleaved full-wave min reductions.
        #pragma unroll
        for (int j = 0; j < RB; ++j) rmin[j] = wave_min64(rmin[j], xaddr32);
        #pragma unroll
        for (int j = 0; j < RB; ++j) rowsum += x[j].w + rmin[j];
    }

    // Publish per-wave partials.
    #pragma unroll
    for (int i = 0; i < CPL; ++i) colminS[wave][i * 64 + lane] = colmin[i];
    if (lane == 0) rowsumS[wave] = rowsum;
    __syncthreads();

    // Cross-wave column-min merge + sum (1 col per thread).
    {
        const int n = tid;
        float cm = colminS[0][n];
        #pragma unroll
        for (int w = 1; w < NWAVES; ++w) cm = fminf(cm, colminS[w][n]);
        float csum = cm;
        #pragma unroll
        for (int off = 32; off > 0; off >>= 1)
            csum += __shfl_xor(csum, off, 64);
        if (lane == 0) csumS[wave] = csum;
    }
    __syncthreads();

    if (tid == 0) {
        float rs = 0.0f, cs = 0.0f;
        #pragma unroll
        for (int w = 0; w < NWAVES; ++w) { rs += rowsumS[w]; cs += csumS[w]; }
        atomicAdd(out, rs * inv_bpm + cs * inv_bpn);
    }
}

extern "C" void kernel_launch(void* const* d_in, const int* in_sizes, int n_in,
                              void* d_out, int out_size, void* d_ws, size_t ws_size,
                              hipStream_t stream) {
    const float* nrf = (const float*)d_in[0];  // (B,P,N,3)
    const float* rp  = (const float*)d_in[1];  // (B,P,M,3)
    float* out = (float*)d_out;

    const int BP = in_sizes[1] / (MM * 3);     // 256
    const float inv_bpm = 1.0f / (float)(BP * MM);
    const float inv_bpn = 1.0f / (float)(BP * NN);

    (void)hipMemsetAsync(out, 0, sizeof(float), stream);
    chamfer_kernel<<<BP, THREADS, 0, stream>>>(nrf, rp, out, inv_bpm, inv_bpn);
}